// Round 8
// baseline (86.440 us; speedup 1.0000x reference)
//
#include <hip/hip_runtime.h>

// Neo-Hookean constants (match reference)
#define MU_C   3846.1538461538462f   // E/(2(1+nu))
#define LM_C   5769.2307692307695f   // E*nu/((1+nu)(1-2nu))
#define LOGC   (MU_C + 0.5f * LM_C)  // combined log coefficient
#define EPS_C  1e-10f

// B=4, N_QUAD=4, NPE=4 fixed by the reference problem.
// v7: persistent blocks (grid ~= 8/CU), thread=(element,batch) as in v2,
// grid-stride over 64-element tiles, register accumulation across tiles.
#define PBLOCKS 2048   // 8 blocks/CU * 256 CU

// Transpose u (B, n_nodes, 3) -> ut (n_nodes, B, 4) padded float4 (64B/node).
__global__ __launch_bounds__(256) void nh_transpose_u_pad(
    const float* __restrict__ u, float4* __restrict__ ut, int n_nodes)
{
    const int i = blockIdx.x * 256 + threadIdx.x;
    if (i >= n_nodes) return;
    float4* q = ut + (size_t)i * 4;
    #pragma unroll
    for (int b = 0; b < 4; ++b) {
        const float* p = u + ((size_t)b * n_nodes + i) * 3;
        q[b] = make_float4(p[0], p[1], p[2], 0.f);
    }
}

// energy of one element/batch from registers
__device__ __forceinline__ float nh_energy(
    const float4* dn,      // 12 float4 = 48-float dN slab, d[(q*4+n)*3+j]
    const float4* uu,      // 4 float4 node displacements (xyz used)
    const float*  wqv)     // detJ*qw per quad point
{
    const float* d  = reinterpret_cast<const float*>(dn);
    const float* us = reinterpret_cast<const float*>(uu);
    float a = 0.f;
    #pragma unroll
    for (int q = 0; q < 4; ++q) {
        float F[3][3];
        #pragma unroll
        for (int i = 0; i < 3; ++i) {
            #pragma unroll
            for (int j = 0; j < 3; ++j) {
                float g = 0.f;
                #pragma unroll
                for (int n = 0; n < 4; ++n)
                    g = fmaf(us[n * 4 + i], d[(q*4 + n)*3 + j], g);
                F[i][j] = g + ((i == j) ? 1.f : 0.f);
            }
        }
        const float J =
              F[0][0] * (F[1][1]*F[2][2] - F[1][2]*F[2][1])
            - F[0][1] * (F[1][0]*F[2][2] - F[1][2]*F[2][0])
            + F[0][2] * (F[1][0]*F[2][1] - F[1][1]*F[2][0]);
        float IC = 0.f;
        #pragma unroll
        for (int i = 0; i < 3; ++i)
            #pragma unroll
            for (int j = 0; j < 3; ++j)
                IC = fmaf(F[i][j], F[i][j], IC);
        const float lj = __logf(fmaxf(J, EPS_C));
        const float W = 0.5f * MU_C * (IC - 3.f)
                      + 0.25f * LM_C * fmaf(J, J, -1.f)
                      - LOGC * lj;
        a = fmaf(W, wqv[q], a);
    }
    return a;
}

__global__ __launch_bounds__(256, 7) void nh_partial_v7(
    const float4* __restrict__ ut,        // (n_nodes, 4) padded float4
    const int*    __restrict__ elements,  // (n_elem, 4)
    const float*  __restrict__ dN_dx,     // (n_elem, 4, 4, 3)
    const float*  __restrict__ detJ,      // (n_elem, 4)
    const float*  __restrict__ qw,        // (4,)
    float* __restrict__ partial,          // (gridDim.x, 4)
    int n_elem, int ntiles)
{
    const int t = threadIdx.x;
    const int b = t & 3;
    const int p = t >> 2;                 // element-within-tile: 0..63

    const int4*   elp = reinterpret_cast<const int4*>(elements);
    const float4* djp = reinterpret_cast<const float4*>(detJ);
    const float4* dnp = reinterpret_cast<const float4*>(dN_dx);
    const float4  w4  = *reinterpret_cast<const float4*>(qw);

    float acc = 0.f;

    for (int tile = blockIdx.x; tile < ntiles; tile += gridDim.x) {
        const int e = tile * 64 + p;
        if (e >= n_elem) continue;

        const int4   nd = elp[e];
        const float4 dj = djp[e];

        float4 dv[12];
        const float4* dptr = dnp + (size_t)e * 12;
        #pragma unroll
        for (int k = 0; k < 12; ++k) dv[k] = dptr[k];

        // gather: 32-bit indices; 4 batch-lanes of an element cover one 64B line
        float4 uu[4];
        uu[0] = ut[nd.x * 4 + b];
        uu[1] = ut[nd.y * 4 + b];
        uu[2] = ut[nd.z * 4 + b];
        uu[3] = ut[nd.w * 4 + b];

        const float wqv[4] = {dj.x * w4.x, dj.y * w4.y, dj.z * w4.z, dj.w * w4.w};

        acc += nh_energy(dv, uu, wqv);
    }

    // reduce across lanes with the same b (stride-4 groups): offsets 32..4
    #pragma unroll
    for (int off = 32; off >= 4; off >>= 1)
        acc += __shfl_down(acc, off);
    // lanes 0..3 now hold this wave's batch sums

    __shared__ float s_red[4][4];
    const int lane = t & 63;
    const int wid  = t >> 6;
    if (lane < 4) s_red[wid][lane] = acc;
    __syncthreads();
    if (t < 4)
        partial[(size_t)blockIdx.x * 4 + t] =
            (s_red[0][t] + s_red[1][t]) + (s_red[2][t] + s_red[3][t]);
}

__global__ __launch_bounds__(256) void nh_final(
    const float* __restrict__ partial,  // (nparts, 4)
    float* __restrict__ out,            // (4,)
    int nparts)
{
    float accb[4] = {0.f, 0.f, 0.f, 0.f};
    for (int i = threadIdx.x; i < nparts; i += 256) {
        const float4 p = reinterpret_cast<const float4*>(partial)[i];
        accb[0] += p.x; accb[1] += p.y; accb[2] += p.z; accb[3] += p.w;
    }

    #pragma unroll
    for (int b = 0; b < 4; ++b) {
        float v = accb[b];
        #pragma unroll
        for (int off = 32; off > 0; off >>= 1)
            v += __shfl_down(v, off);
        accb[b] = v;
    }

    __shared__ float lds[4][4];
    const int lane = threadIdx.x & 63;
    const int wid  = threadIdx.x >> 6;
    if (lane == 0) {
        #pragma unroll
        for (int b = 0; b < 4; ++b) lds[wid][b] = accb[b];
    }
    __syncthreads();
    if (threadIdx.x == 0) {
        #pragma unroll
        for (int b = 0; b < 4; ++b)
            out[b] = (lds[0][b] + lds[1][b]) + (lds[2][b] + lds[3][b]);
    }
}

extern "C" void kernel_launch(void* const* d_in, const int* in_sizes, int n_in,
                              void* d_out, int out_size, void* d_ws, size_t ws_size,
                              hipStream_t stream) {
    const float* u        = (const float*)d_in[0];
    const int*   elements = (const int*)d_in[1];
    const float* dN_dx    = (const float*)d_in[2];
    const float* detJ     = (const float*)d_in[3];
    const float* qw       = (const float*)d_in[4];
    float* out = (float*)d_out;

    const int B       = out_size;            // 4
    const int n_nodes = in_sizes[0] / (3 * B);
    const int n_elem  = in_sizes[1] / 4;

    const int threads = 256;
    const int ntiles  = (n_elem + 63) / 64;
    const int nblocks = (ntiles < PBLOCKS) ? ntiles : PBLOCKS;

    const size_t ut_bytes = (size_t)n_nodes * 4 * sizeof(float4);  // padded
    float4* ut     = (float4*)d_ws;
    float* partial = (float*)((char*)d_ws + ut_bytes);

    const int tb = (n_nodes + threads - 1) / threads;
    nh_transpose_u_pad<<<tb, threads, 0, stream>>>(u, ut, n_nodes);

    nh_partial_v7<<<nblocks, threads, 0, stream>>>(ut, elements, dN_dx, detJ, qw,
                                                   partial, n_elem, ntiles);
    nh_final<<<1, threads, 0, stream>>>(partial, out, nblocks);
}

// Round 9
// 61.470 us; speedup vs baseline: 1.4062x; 1.4062x over previous
//
#include <hip/hip_runtime.h>

// Neo-Hookean constants (match reference)
#define MU_C   3846.1538461538462f   // E/(2(1+nu))
#define LM_C   5769.2307692307695f   // E*nu/((1+nu)(1-2nu))
#define LOGC   (MU_C + 0.5f * LM_C)  // combined log coefficient
#define EPS_C  1e-10f

// B=4, N_QUAD=4, NPE=4 fixed by the reference problem.
// v8: persistent blocks (v7) WITHOUT the register cap (v7's launch_bounds(256,7)
// forced VGPR=36 -> scratch spill: WRITE 43MB, FETCH +80MB, VALUBusy 17%).
#define PBLOCKS 2048   // 8 blocks/CU * 256 CU (queue depth; ~5 resident/CU)

// Transpose u (B, n_nodes, 3) -> ut (n_nodes, B, 4) padded float4 (64B/node).
__global__ __launch_bounds__(256) void nh_transpose_u_pad(
    const float* __restrict__ u, float4* __restrict__ ut, int n_nodes)
{
    const int i = blockIdx.x * 256 + threadIdx.x;
    if (i >= n_nodes) return;
    float4* q = ut + (size_t)i * 4;
    #pragma unroll
    for (int b = 0; b < 4; ++b) {
        const float* p = u + ((size_t)b * n_nodes + i) * 3;
        q[b] = make_float4(p[0], p[1], p[2], 0.f);
    }
}

// energy of one element/batch from registers
__device__ __forceinline__ float nh_energy(
    const float4* dn,      // 12 float4 = 48-float dN slab, d[(q*4+n)*3+j]
    const float4* uu,      // 4 float4 node displacements (xyz used)
    const float*  wqv)     // detJ*qw per quad point
{
    const float* d  = reinterpret_cast<const float*>(dn);
    const float* us = reinterpret_cast<const float*>(uu);
    float a = 0.f;
    #pragma unroll
    for (int q = 0; q < 4; ++q) {
        float F[3][3];
        #pragma unroll
        for (int i = 0; i < 3; ++i) {
            #pragma unroll
            for (int j = 0; j < 3; ++j) {
                float g = 0.f;
                #pragma unroll
                for (int n = 0; n < 4; ++n)
                    g = fmaf(us[n * 4 + i], d[(q*4 + n)*3 + j], g);
                F[i][j] = g + ((i == j) ? 1.f : 0.f);
            }
        }
        const float J =
              F[0][0] * (F[1][1]*F[2][2] - F[1][2]*F[2][1])
            - F[0][1] * (F[1][0]*F[2][2] - F[1][2]*F[2][0])
            + F[0][2] * (F[1][0]*F[2][1] - F[1][1]*F[2][0]);
        float IC = 0.f;
        #pragma unroll
        for (int i = 0; i < 3; ++i)
            #pragma unroll
            for (int j = 0; j < 3; ++j)
                IC = fmaf(F[i][j], F[i][j], IC);
        const float lj = __logf(fmaxf(J, EPS_C));
        const float W = 0.5f * MU_C * (IC - 3.f)
                      + 0.25f * LM_C * fmaf(J, J, -1.f)
                      - LOGC * lj;
        a = fmaf(W, wqv[q], a);
    }
    return a;
}

__global__ __launch_bounds__(256) void nh_partial_v8(
    const float4* __restrict__ ut,        // (n_nodes, 4) padded float4
    const int*    __restrict__ elements,  // (n_elem, 4)
    const float*  __restrict__ dN_dx,     // (n_elem, 4, 4, 3)
    const float*  __restrict__ detJ,      // (n_elem, 4)
    const float*  __restrict__ qw,        // (4,)
    float* __restrict__ partial,          // (gridDim.x, 4)
    int n_elem, int ntiles)
{
    const int t = threadIdx.x;
    const int b = t & 3;
    const int p = t >> 2;                 // element-within-tile: 0..63

    const int4*   elp = reinterpret_cast<const int4*>(elements);
    const float4* djp = reinterpret_cast<const float4*>(detJ);
    const float4* dnp = reinterpret_cast<const float4*>(dN_dx);
    const float4  w4  = *reinterpret_cast<const float4*>(qw);

    float acc = 0.f;

    for (int tile = blockIdx.x; tile < ntiles; tile += gridDim.x) {
        const int e = tile * 64 + p;
        if (e >= n_elem) continue;

        const int4   nd = elp[e];
        const float4 dj = djp[e];

        float4 dv[12];
        const float4* dptr = dnp + (size_t)e * 12;
        #pragma unroll
        for (int k = 0; k < 12; ++k) dv[k] = dptr[k];

        // gather: 32-bit indices; 4 batch-lanes of an element cover one 64B line
        float4 uu[4];
        uu[0] = ut[nd.x * 4 + b];
        uu[1] = ut[nd.y * 4 + b];
        uu[2] = ut[nd.z * 4 + b];
        uu[3] = ut[nd.w * 4 + b];

        const float wqv[4] = {dj.x * w4.x, dj.y * w4.y, dj.z * w4.z, dj.w * w4.w};

        acc += nh_energy(dv, uu, wqv);
    }

    // reduce across lanes with the same b (stride-4 groups): offsets 32..4
    #pragma unroll
    for (int off = 32; off >= 4; off >>= 1)
        acc += __shfl_down(acc, off);
    // lanes 0..3 now hold this wave's batch sums

    __shared__ float s_red[4][4];
    const int lane = t & 63;
    const int wid  = t >> 6;
    if (lane < 4) s_red[wid][lane] = acc;
    __syncthreads();
    if (t < 4)
        partial[(size_t)blockIdx.x * 4 + t] =
            (s_red[0][t] + s_red[1][t]) + (s_red[2][t] + s_red[3][t]);
}

__global__ __launch_bounds__(256) void nh_final(
    const float* __restrict__ partial,  // (nparts, 4)
    float* __restrict__ out,            // (4,)
    int nparts)
{
    float accb[4] = {0.f, 0.f, 0.f, 0.f};
    for (int i = threadIdx.x; i < nparts; i += 256) {
        const float4 p = reinterpret_cast<const float4*>(partial)[i];
        accb[0] += p.x; accb[1] += p.y; accb[2] += p.z; accb[3] += p.w;
    }

    #pragma unroll
    for (int b = 0; b < 4; ++b) {
        float v = accb[b];
        #pragma unroll
        for (int off = 32; off > 0; off >>= 1)
            v += __shfl_down(v, off);
        accb[b] = v;
    }

    __shared__ float lds[4][4];
    const int lane = threadIdx.x & 63;
    const int wid  = threadIdx.x >> 6;
    if (lane == 0) {
        #pragma unroll
        for (int b = 0; b < 4; ++b) lds[wid][b] = accb[b];
    }
    __syncthreads();
    if (threadIdx.x == 0) {
        #pragma unroll
        for (int b = 0; b < 4; ++b)
            out[b] = (lds[0][b] + lds[1][b]) + (lds[2][b] + lds[3][b]);
    }
}

extern "C" void kernel_launch(void* const* d_in, const int* in_sizes, int n_in,
                              void* d_out, int out_size, void* d_ws, size_t ws_size,
                              hipStream_t stream) {
    const float* u        = (const float*)d_in[0];
    const int*   elements = (const int*)d_in[1];
    const float* dN_dx    = (const float*)d_in[2];
    const float* detJ     = (const float*)d_in[3];
    const float* qw       = (const float*)d_in[4];
    float* out = (float*)d_out;

    const int B       = out_size;            // 4
    const int n_nodes = in_sizes[0] / (3 * B);
    const int n_elem  = in_sizes[1] / 4;

    const int threads = 256;
    const int ntiles  = (n_elem + 63) / 64;
    const int nblocks = (ntiles < PBLOCKS) ? ntiles : PBLOCKS;

    const size_t ut_bytes = (size_t)n_nodes * 4 * sizeof(float4);  // padded
    float4* ut     = (float4*)d_ws;
    float* partial = (float*)((char*)d_ws + ut_bytes);

    const int tb = (n_nodes + threads - 1) / threads;
    nh_transpose_u_pad<<<tb, threads, 0, stream>>>(u, ut, n_nodes);

    nh_partial_v8<<<nblocks, threads, 0, stream>>>(ut, elements, dN_dx, detJ, qw,
                                                   partial, n_elem, ntiles);
    nh_final<<<1, threads, 0, stream>>>(partial, out, nblocks);
}